// Round 1
// baseline (157.011 us; speedup 1.0000x reference)
//
#include <hip/hip_runtime.h>

// Problem constants (from reference)
#define SPP   16
#define SH    256
#define SW    256
#define H_IMG 1024
#define W_IMG 1024
#define CH    3
#define BATCH 4

// One thread per (batch, sensor_y, sensor_x).
// Geometry (tanh warp, bilinear weights, det) computed once per spp,
// shared across the 3 channels. Output = sum(sample*det)/sum(det)
// (the /SPP in weighted and area cancels).
__global__ __launch_bounds__(256) void foveated_kernel(
    const float* __restrict__ img,
    const float* __restrict__ t_ptr,
    const float* __restrict__ jitter,
    float* __restrict__ out)
{
    const int tid = blockIdx.x * blockDim.x + threadIdx.x;
    const int sx = tid & (SW - 1);
    const int sy = (tid >> 8) & (SH - 1);
    const int b  = tid >> 16;

    const float step = 2.0f / 256.0f;       // exactly representable (2^-7)
    const float tt   = t_ptr[0];
    const float s    = tanhf(tt);
    const float inv_s = 1.0f / s;

    const float px = -1.0f + sx * step;
    const float py = -1.0f + sy * step;

    float acc0 = 0.0f, acc1 = 0.0f, acc2 = 0.0f, dsum = 0.0f;

    const size_t plane = (size_t)H_IMG * W_IMG;
    const float* __restrict__ p0 = img + (size_t)(b * CH + 0) * plane;
    const float* __restrict__ p1 = p0 + plane;
    const float* __restrict__ p2 = p1 + plane;

    const float2* __restrict__ jit2 = (const float2*)jitter;
    const int jbase = sy * SW + sx;

    #pragma unroll 4
    for (int sp = 0; sp < SPP; ++sp) {
        const float2 j = jit2[sp * (SH * SW) + jbase];
        const float posx = px + j.x * step;
        const float posy = py + j.y * step;

        const float thx = tanhf(tt * posx);
        const float thy = tanhf(tt * posy);
        const float warpx = thx * inv_s;
        const float warpy = thy * inv_s;
        const float ddx = tt * (1.0f - thx * thx) * inv_s;
        const float ddy = tt * (1.0f - thy * thy) * inv_s;
        const float det = ddx * ddy;

        float gx = (warpx + 1.0f) * (W_IMG * 0.5f) - 0.5f;
        float gy = (warpy + 1.0f) * (H_IMG * 0.5f) - 0.5f;
        gx = fminf(fmaxf(gx, 0.0f), (float)(W_IMG - 1));
        gy = fminf(fmaxf(gy, 0.0f), (float)(H_IMG - 1));

        const float x0f = floorf(gx);
        const float y0f = floorf(gy);
        const float fx = gx - x0f;
        const float fy = gy - y0f;
        const int x0 = (int)x0f;              // in [0, W-1] after clamp
        const int y0 = (int)y0f;
        const int x1 = min(x0 + 1, W_IMG - 1);
        const int y1 = min(y0 + 1, H_IMG - 1);

        const float w00 = (1.0f - fx) * (1.0f - fy) * det;
        const float w01 = fx * (1.0f - fy) * det;
        const float w10 = (1.0f - fx) * fy * det;
        const float w11 = fx * fy * det;

        dsum += det;

        const int i00 = y0 * W_IMG + x0;
        const int i01 = y0 * W_IMG + x1;
        const int i10 = y1 * W_IMG + x0;
        const int i11 = y1 * W_IMG + x1;

        acc0 += p0[i00] * w00 + p0[i01] * w01 + p0[i10] * w10 + p0[i11] * w11;
        acc1 += p1[i00] * w00 + p1[i01] * w01 + p1[i10] * w10 + p1[i11] * w11;
        acc2 += p2[i00] * w00 + p2[i01] * w01 + p2[i10] * w10 + p2[i11] * w11;
    }

    const float inv_d = 1.0f / dsum;
    const int pix = sy * SW + sx;
    const size_t obase = (size_t)b * CH * (SH * SW) + pix;
    out[obase]                   = acc0 * inv_d;
    out[obase + (SH * SW)]       = acc1 * inv_d;
    out[obase + 2 * (SH * SW)]   = acc2 * inv_d;
}

extern "C" void kernel_launch(void* const* d_in, const int* in_sizes, int n_in,
                              void* d_out, int out_size, void* d_ws, size_t ws_size,
                              hipStream_t stream) {
    const float* img    = (const float*)d_in[0];
    const float* t      = (const float*)d_in[1];
    const float* jitter = (const float*)d_in[2];
    float* out          = (float*)d_out;

    const int total  = BATCH * SH * SW;      // 262144 threads
    const int block  = 256;
    const int grid   = total / block;        // 1024 blocks

    hipLaunchKernelGGL(foveated_kernel, dim3(grid), dim3(block), 0, stream,
                       img, t, jitter, out);
}

// Round 2
// 109.090 us; speedup vs baseline: 1.4393x; 1.4393x over previous
//
#include <hip/hip_runtime.h>

// Problem constants (from reference)
#define SPP   16
#define SH    256
#define SW    256
#define H_IMG 1024
#define W_IMG 1024
#define CH    3
#define BATCH 4

// Mapping:
//   grid = 2048 blocks x 256 threads
//   logical block L (after XCD swizzle): b = L>>9, sy = (L>>1)&255, xh = L&1
//   thread: lane = th&31 (pixel within 32-px group), half = (th>>5)&1 (spp half),
//           grp = th>>6 (32-px group). sx = xh*128 + grp*32 + lane.
//   Each thread does 8 spp; pair (lane, lane+32) reduced via __shfl_xor(32).
//
// Border handling: instead of clamping x1/y1, rebase xb=min(x0,W-2) and let
// fx = gx - xb reach 1.0 at the right/bottom border. Identical algebra to the
// reference (at gx==W-1 exactly: fx=1 -> all weight on the W-1 texel), and the
// float2 load [xb, xb+1] is always in-bounds.
__global__ __launch_bounds__(256) void foveated_kernel(
    const float* __restrict__ img,
    const float* __restrict__ t_ptr,
    const float* __restrict__ jitter,
    float* __restrict__ out)
{
    // XCD-aware swizzle: blockIdx%8 is (heuristically) the XCD; give each XCD
    // a contiguous slab of 256 logical blocks = half a batch of sensor rows.
    const int L  = (blockIdx.x & 7) * 256 + (blockIdx.x >> 3);
    const int b  = L >> 9;
    const int sy = (L >> 1) & (SH - 1);
    const int xh = L & 1;

    const int th   = threadIdx.x;
    const int lane = th & 31;
    const int half = (th >> 5) & 1;
    const int grp  = th >> 6;
    const int sx   = xh * 128 + grp * 32 + lane;

    const float step  = 2.0f / 256.0f;
    const float tt    = t_ptr[0];
    const float inv_s = 1.0f / tanhf(tt);

    const float px = -1.0f + sx * step;
    const float py = -1.0f + sy * step;

    float acc0 = 0.0f, acc1 = 0.0f, acc2 = 0.0f, dsum = 0.0f;

    const size_t plane = (size_t)H_IMG * W_IMG;
    const float* __restrict__ p0 = img + (size_t)(b * CH) * plane;
    const float* __restrict__ p1 = p0 + plane;
    const float* __restrict__ p2 = p1 + plane;

    const float2* __restrict__ jit2 = (const float2*)jitter;
    const int jbase = sy * SW + sx;

    #pragma unroll 4
    for (int k = 0; k < SPP / 2; ++k) {
        const int sp = half * (SPP / 2) + k;
        const float2 j = jit2[sp * (SH * SW) + jbase];
        const float posx = px + j.x * step;
        const float posy = py + j.y * step;

        const float thx = tanhf(tt * posx);
        const float thy = tanhf(tt * posy);
        const float ddx = tt * (1.0f - thx * thx) * inv_s;
        const float ddy = tt * (1.0f - thy * thy) * inv_s;
        const float det = ddx * ddy;

        float gx = (thx * inv_s + 1.0f) * (W_IMG * 0.5f) - 0.5f;
        float gy = (thy * inv_s + 1.0f) * (H_IMG * 0.5f) - 0.5f;
        gx = fminf(fmaxf(gx, 0.0f), (float)(W_IMG - 1));
        gy = fminf(fmaxf(gy, 0.0f), (float)(H_IMG - 1));

        const int xb = min((int)gx, W_IMG - 2);   // trunc == floor (gx >= 0)
        const int yb = min((int)gy, H_IMG - 2);
        const float fx = gx - (float)xb;          // in [0, 1]
        const float fy = gy - (float)yb;

        const float w00 = (1.0f - fx) * (1.0f - fy) * det;
        const float w01 = fx * (1.0f - fy) * det;
        const float w10 = (1.0f - fx) * fy * det;
        const float w11 = fx * fy * det;
        dsum += det;

        const int i0 = yb * W_IMG + xb;           // row yb, cols xb..xb+1
        const int i1 = i0 + W_IMG;                // row yb+1

        {
            const float2 a = *(const float2*)(p0 + i0);
            const float2 c = *(const float2*)(p0 + i1);
            acc0 += a.x * w00 + a.y * w01 + c.x * w10 + c.y * w11;
        }
        {
            const float2 a = *(const float2*)(p1 + i0);
            const float2 c = *(const float2*)(p1 + i1);
            acc1 += a.x * w00 + a.y * w01 + c.x * w10 + c.y * w11;
        }
        {
            const float2 a = *(const float2*)(p2 + i0);
            const float2 c = *(const float2*)(p2 + i1);
            acc2 += a.x * w00 + a.y * w01 + c.x * w10 + c.y * w11;
        }
    }

    // Combine the two spp halves: pair (lane, lane+32) within the wave.
    acc0 += __shfl_xor(acc0, 32);
    acc1 += __shfl_xor(acc1, 32);
    acc2 += __shfl_xor(acc2, 32);
    dsum += __shfl_xor(dsum, 32);

    if (half == 0) {
        const float inv_d = 1.0f / dsum;
        const int pix = sy * SW + sx;
        const size_t obase = (size_t)b * CH * (SH * SW) + pix;
        out[obase]                 = acc0 * inv_d;
        out[obase + (SH * SW)]     = acc1 * inv_d;
        out[obase + 2 * (SH * SW)] = acc2 * inv_d;
    }
}

extern "C" void kernel_launch(void* const* d_in, const int* in_sizes, int n_in,
                              void* d_out, int out_size, void* d_ws, size_t ws_size,
                              hipStream_t stream) {
    const float* img    = (const float*)d_in[0];
    const float* t      = (const float*)d_in[1];
    const float* jitter = (const float*)d_in[2];
    float* out          = (float*)d_out;

    const int grid  = 2048;   // 4 batch * 256 rows * 2 x-halves
    const int block = 256;

    hipLaunchKernelGGL(foveated_kernel, dim3(grid), dim3(block), 0, stream,
                       img, t, jitter, out);
}